// Round 9
// baseline (2012.407 us; speedup 1.0000x reference)
//
#include <hip/hip_runtime.h>

#define NB   8
#define NP   8192
#define NS   2048
#define NK   16
#define DIN  64
#define DOUT 128
#define BN_EPS 1e-5f

#define MT   512            // mega-kernel block size
#define NW   248            // worker blocks (grid = 8 fps + 248 workers = 256 CUs)
#define FP   (NP / MT)      // 16 fps points per thread
#define FH   (FP / 2)       // 8 float2 pairs
#define FW   (MT / 64)      // 8 waves
#define KJ   (NP / MT)      // 16 knn points per thread
#define KBINS 64
#define MAXC 512

typedef float v2f __attribute__((ext_vector_type(2)));

// ---------------- f64-packed argmax helpers --------------------------------------
// packed u64 = (fp32 dist bits << 32) | ~idx, as double (sign bit 0 -> numeric
// order == u64 order): fmax == (max dist, tie -> min idx).
__device__ __forceinline__ double pack_di(float d, unsigned lo)
{
    unsigned long long u = ((unsigned long long)__float_as_uint(d) << 32) | lo;
    return __longlong_as_double((long long)u);
}

template<int CTRL, int RMASK>
__device__ __forceinline__ double dpp_max_f64(double v)
{
    unsigned long long u = (unsigned long long)__double_as_longlong(v);
    unsigned hi = (unsigned)(u >> 32), lo = (unsigned)u;
    unsigned th = (unsigned)__builtin_amdgcn_update_dpp((int)hi, (int)hi, CTRL, RMASK, 0xF, false);
    unsigned tl = (unsigned)__builtin_amdgcn_update_dpp((int)lo, (int)lo, CTRL, RMASK, 0xF, false);
    double o = __longlong_as_double((long long)(((unsigned long long)th << 32) | tl));
    return fmax(v, o);
}

__device__ __forceinline__ int knn_bin(float d)
{
    int e = (int)(__float_as_uint(d) >> 23) - 90;   // monotone, clamped octave bins
    return e < 0 ? 0 : (e > 63 ? 63 : e);
}

// ---------------- mega kernel: 8 fps producers + 248 persistent workers --------
struct FpsS {
    float4 sxyz[NP];                    // 128 KB
    int sel[NS];                        // 8 KB
    unsigned long long rv64[2][FW];
};
struct KnnS {
    float sdist[NP];                    // 32 KB
    unsigned hist[32][KBINS];           // 8 KB
    float cd[MAXC];
    int   ci[MAXC];
    int   sidx[NK];
    float sf[NK][DIN];                  // 4 KB gathered feat rows
    float red[4][DOUT];                 // 2 KB cross-group max
    float wt[DIN * DOUT];               // 32 KB folded weights (LDS-resident)
    float cbv[DOUT];                    // 512 B folded bias
    unsigned ccnt;
    int cut;
};
union MegaS { FpsS f; KnnS k; };
// union = ~139 KB -> 1 block/CU; grid 256 -> all blocks co-resident,
// so producer progress never depends on dispatch order (deadlock-safe).

__global__ __launch_bounds__(MT, 1)
void mega_kernel(const float* __restrict__ coords, float* __restrict__ out_coords,
                 const float* __restrict__ feat, const float* __restrict__ W,
                 const float* __restrict__ bias, const float* __restrict__ gamma,
                 const float* __restrict__ beta, const float* __restrict__ rmean,
                 const float* __restrict__ rvar, float* __restrict__ outF,
                 unsigned* __restrict__ flags)
{
#pragma clang fp contract(off)
    __shared__ MegaS smem;
    const int t = threadIdx.x;

    if (blockIdx.x < NB) {
        // ================= FPS producer (1 block per batch) =================
        const int b = blockIdx.x;
        const float* cb = coords + (size_t)b * NP * 3;

        for (int i = t; i < NP; i += MT)
            smem.f.sxyz[i] = make_float4(cb[i * 3 + 0], cb[i * 3 + 1], cb[i * 3 + 2], 0.0f);
        __syncthreads();

        // points as float2 pairs: pair j holds indices t+2j*MT (lo), t+(2j+1)*MT (hi)
        v2f px2[FH], py2[FH], pz2[FH], dist2[FH];
#pragma unroll
        for (int j = 0; j < FH; ++j) {
            float4 plo = smem.f.sxyz[t + (2 * j) * MT];
            float4 phi = smem.f.sxyz[t + (2 * j + 1) * MT];
            px2[j].x = plo.x; px2[j].y = phi.x;
            py2[j].x = plo.y; py2[j].y = phi.y;
            pz2[j].x = plo.z; pz2[j].y = phi.z;
            dist2[j].x = 1e10f; dist2[j].y = 1e10f;
        }

        const int wave = t >> 6, lane = t & 63;
        const unsigned nt = ~(unsigned)t;          // ~(t + k*MT) == nt - k*MT
        int cur = 0;

        for (int s = 0; s < NS; ++s) {
            if (t == 0) smem.f.sel[s] = cur;
            const float4 cc = smem.f.sxyz[cur];
            // negated centroid: px + (-cx) is bit-identical to px - cx
            v2f ncx2 = {-cc.x, -cc.x};
            v2f ncy2 = {-cc.y, -cc.y};
            v2f ncz2 = {-cc.z, -cc.z};

            // packed dist: v_pk ops are double-rate f32; same op order as
            // fmaf(dz,dz,fmaf(dy,dy,dx*dx)) -> bit-identical
            float m0 = -1.0f, m1 = -1.0f;
#pragma unroll
            for (int j = 0; j < FH; ++j) {
                v2f dx2, dy2, dz2, d2;
                asm("v_pk_add_f32 %0, %1, %2" : "=v"(dx2) : "v"(px2[j]), "v"(ncx2));
                asm("v_pk_add_f32 %0, %1, %2" : "=v"(dy2) : "v"(py2[j]), "v"(ncy2));
                asm("v_pk_add_f32 %0, %1, %2" : "=v"(dz2) : "v"(pz2[j]), "v"(ncz2));
                asm("v_pk_mul_f32 %0, %1, %1" : "=v"(d2) : "v"(dx2));
                asm("v_pk_fma_f32 %0, %1, %1, %0" : "+v"(d2) : "v"(dy2));
                asm("v_pk_fma_f32 %0, %1, %1, %0" : "+v"(d2) : "v"(dz2));
                float ndx = fminf(dist2[j].x, d2.x);
                float ndy = fminf(dist2[j].y, d2.y);
                dist2[j].x = ndx; dist2[j].y = ndy;
                m0 = fmaxf(m0, ndx);
                m1 = fmaxf(m1, ndy);
            }
            float m = fmaxf(m0, m1);
            // recover smallest k attaining m: independent compares -> or-tree -> ctz
            unsigned msk = 0;
#pragma unroll
            for (int j = 0; j < FH; ++j) {
                msk |= (dist2[j].x == m) ? (1u << (2 * j))     : 0u;
                msk |= (dist2[j].y == m) ? (1u << (2 * j + 1)) : 0u;
            }
            int kk = __builtin_ctz(msk);
            double best = pack_di(m, nt - (unsigned)(kk * MT));

            // wave argmax: 6 DPP f64-max levels -> lane 63 holds wave max
            best = dpp_max_f64<0xB1,  0xF>(best);  // quad_perm xor1
            best = dpp_max_f64<0x4E,  0xF>(best);  // quad_perm xor2
            best = dpp_max_f64<0x124, 0xF>(best);  // row_ror:4
            best = dpp_max_f64<0x128, 0xF>(best);  // row_ror:8
            best = dpp_max_f64<0x142, 0xA>(best);  // row_bcast15
            best = dpp_max_f64<0x143, 0xC>(best);  // row_bcast31

            int pb = s & 1;
            if (lane == 63) smem.f.rv64[pb][wave] = (unsigned long long)__double_as_longlong(best);
            __syncthreads();

            // cross-wave: b64 read of partial[lane&7]; period-8 values fully
            // reduce in 3 DPP levels (xor1, xor2, ror4) — ror8 was redundant
            double g = __longlong_as_double((long long)smem.f.rv64[pb][lane & 7]);
            g = dpp_max_f64<0xB1,  0xF>(g);
            g = dpp_max_f64<0x4E,  0xF>(g);
            g = dpp_max_f64<0x124, 0xF>(g);
            cur = (int)~(unsigned)(unsigned long long)__double_as_longlong(g);

            // publish a 32-query granule (wave 0 only: program-order release
            // covers the wave's own coord stores)
            if ((s & 31) == 31) {
                int base = s - 31;
                if (t < 32) {
                    float4 p = smem.f.sxyz[smem.f.sel[base + t]];
                    float* dst = out_coords + ((size_t)b * NS + base + t) * 3;
                    dst[0] = p.x; dst[1] = p.y; dst[2] = p.z;
                }
                if (t == 0)
                    __hip_atomic_store(&flags[b * 16], (unsigned)((s + 1) >> 5),
                                       __ATOMIC_RELEASE, __HIP_MEMORY_SCOPE_AGENT);
            }
        }
    } else {
        // ===== persistent worker: knn + fused gather/MLP/max per query =====
        const int wid = blockIdx.x - NB;           // 0..247
        const int c = t & 31;
        const int o = t & (DOUT - 1);
        const int grp = t >> 7;                    // 0..3

        // fold BN into weights, LDS-resident (once per worker block);
        // identical expressions to the old fold kernel -> identical bits
        for (int i = t; i < DIN * DOUT; i += MT) {
            int oo = i & (DOUT - 1), kk = i >> 7;
            smem.k.wt[i] = W[oo * DIN + kk] * (gamma[oo] * rsqrtf(rvar[oo] + BN_EPS));
        }
        if (t < DOUT)
            smem.k.cbv[t] = (bias[t] - rmean[t]) * (gamma[t] * rsqrtf(rvar[t] + BN_EPS)) + beta[t];
        __syncthreads();

        for (int j = wid; j < NB * NS; j += NW) {
            const int s = j >> 3, b = j & 7;       // ascending s per worker
            const int q = b * NS + s;

            if (t == 0) {
                const unsigned need = (unsigned)(s >> 5) + 1;
                while (__hip_atomic_load(&flags[b * 16], __ATOMIC_ACQUIRE,
                                         __HIP_MEMORY_SCOPE_AGENT) < need)
                    __builtin_amdgcn_s_sleep(32);
            }
            __syncthreads();

            const float* cb = coords + (size_t)b * NP * 3;
            const float* qp = out_coords + (size_t)q * 3;
            const float qx = qp[0], qy = qp[1], qz = qp[2];

            for (int i = t; i < 32 * KBINS; i += MT) ((unsigned*)smem.k.hist)[i] = 0;
            if (t == 0) smem.k.ccnt = 0;
            __syncthreads();

            for (int jj = 0; jj < KJ; ++jj) {
                int i = t + jj * MT;
                float dx = cb[i * 3 + 0] - qx, dy = cb[i * 3 + 1] - qy, dz = cb[i * 3 + 2] - qz;
                float d = fmaf(dz, dz, fmaf(dy, dy, dx * dx));
                smem.k.sdist[i] = d;
                atomicAdd(&smem.k.hist[c][knn_bin(d)], 1u);
            }
            __syncthreads();

            if (t < 64) {
                unsigned total = 0;
#pragma unroll
                for (int cc = 0; cc < 32; ++cc) total += smem.k.hist[cc][t];
                unsigned incl = total;
#pragma unroll
                for (int off = 1; off < 64; off <<= 1) {
                    unsigned n = __shfl_up(incl, off);
                    if (t >= off) incl += n;
                }
                unsigned excl = incl - total;
                if (excl < NK && incl >= NK) smem.k.cut = t;
            }
            __syncthreads();

            const int cut = smem.k.cut;
            for (int jj = 0; jj < KJ; ++jj) {
                int i = t + jj * MT;
                float d = smem.k.sdist[i];
                if (knn_bin(d) <= cut) {
                    unsigned p = atomicAdd(&smem.k.ccnt, 1u);
                    if (p < MAXC) { smem.k.cd[p] = d; smem.k.ci[p] = i; }
                }
            }
            __syncthreads();

            // parallel rank-select: rank = #{(dj,ij) < (d,i)}; unique ranks -> LDS
            int cnt = (int)(smem.k.ccnt < (unsigned)MAXC ? smem.k.ccnt : (unsigned)MAXC);
            for (int p = t; p < cnt; p += MT) {
                float d = smem.k.cd[p]; int idx = smem.k.ci[p];
                int rank = 0;
                for (int jj = 0; jj < cnt; ++jj) {
                    float dj = smem.k.cd[jj]; int ij = smem.k.ci[jj];
                    rank += (dj < d || (dj == d && ij < idx)) ? 1 : 0;
                }
                if (rank < NK) smem.k.sidx[rank] = idx;
            }
            __syncthreads();

            // gather 16 neighbor feat rows (coalesced 256-B rows)
#pragma unroll
            for (int rr = 0; rr < 2; ++rr) {
                int row = (t >> 6) + rr * 8;       // 0..15
                smem.k.sf[row][t & 63] =
                    feat[((size_t)b * NP + smem.k.sidx[row]) * DIN + (t & 63)];
            }
            __syncthreads();

            // fused MLP+relu+max: thread handles out-channel o, neighbors
            // {grp, grp+4, grp+8, grp+12}; cross-group max via LDS
            const float cb0 = smem.k.cbv[o];
            float mx = -3.4e38f;
#pragma unroll
            for (int nn = 0; nn < 4; ++nn) {
                const float4* f4 = (const float4*)smem.k.sf[grp + nn * 4];
                float acc = cb0;
#pragma unroll
                for (int k4 = 0; k4 < DIN / 4; ++k4) {
                    float4 f = f4[k4];
                    acc = fmaf(f.x, smem.k.wt[(k4 * 4 + 0) * DOUT + o], acc);
                    acc = fmaf(f.y, smem.k.wt[(k4 * 4 + 1) * DOUT + o], acc);
                    acc = fmaf(f.z, smem.k.wt[(k4 * 4 + 2) * DOUT + o], acc);
                    acc = fmaf(f.w, smem.k.wt[(k4 * 4 + 3) * DOUT + o], acc);
                }
                mx = fmaxf(mx, fmaxf(acc, 0.0f));
            }
            smem.k.red[grp][o] = mx;
            __syncthreads();

            if (t < DOUT) {
                float v = fmaxf(fmaxf(smem.k.red[0][t], smem.k.red[1][t]),
                                fmaxf(smem.k.red[2][t], smem.k.red[3][t]));
                outF[(size_t)q * DOUT + t] = v;
            }
            __syncthreads();
        }
    }
}

extern "C" void kernel_launch(void* const* d_in, const int* in_sizes, int n_in,
                              void* d_out, int out_size, void* d_ws, size_t ws_size,
                              hipStream_t stream)
{
    const float* coords = (const float*)d_in[0];
    const float* feat   = (const float*)d_in[1];
    const float* W      = (const float*)d_in[2];
    const float* bias   = (const float*)d_in[3];
    const float* gamma  = (const float*)d_in[4];
    const float* beta   = (const float*)d_in[5];
    const float* rmean  = (const float*)d_in[6];
    const float* rvar   = (const float*)d_in[7];

    float* out_coords = (float*)d_out;                    // [8,2048,3]
    float* out_feat   = out_coords + (size_t)NB * NS * 3; // [8,2048,128]

    unsigned* flags = (unsigned*)d_ws;                    // 8 flags, 64B apart

    hipMemsetAsync(flags, 0, 8 * 16 * sizeof(unsigned), stream);
    mega_kernel<<<NB + NW, MT, 0, stream>>>(
        coords, out_coords, feat, W, bias, gamma, beta, rmean, rvar,
        out_feat, flags);
}

// Round 10
// 1890.726 us; speedup vs baseline: 1.0644x; 1.0644x over previous
//
#include <hip/hip_runtime.h>

#define NB   8
#define NP   8192
#define NS   2048
#define NK   16
#define DIN  64
#define DOUT 128
#define BN_EPS 1e-5f

#define MT   512            // mega-kernel block size
#define NW   248            // worker blocks (grid = 8 fps + 248 workers = 256 CUs)
#define FP   (NP / MT)      // 16 fps points per thread
#define FH   (FP / 2)       // 8 float2 pairs
#define FW   (MT / 64)      // 8 waves
#define KJ   (NP / MT)      // 16 knn points per thread
#define KBINS 64
#define MAXC 512

typedef float v2f __attribute__((ext_vector_type(2)));

// ---------------- f64-packed argmax helpers --------------------------------------
// packed u64 = (fp32 dist bits << 32) | ~idx, as double (sign bit 0 -> numeric
// order == u64 order): fmax == (max dist, tie -> min idx).
__device__ __forceinline__ double pack_di(float d, unsigned lo)
{
    unsigned long long u = ((unsigned long long)__float_as_uint(d) << 32) | lo;
    return __longlong_as_double((long long)u);
}

template<int CTRL, int RMASK>
__device__ __forceinline__ double dpp_max_f64(double v)
{
    unsigned long long u = (unsigned long long)__double_as_longlong(v);
    unsigned hi = (unsigned)(u >> 32), lo = (unsigned)u;
    unsigned th = (unsigned)__builtin_amdgcn_update_dpp((int)hi, (int)hi, CTRL, RMASK, 0xF, false);
    unsigned tl = (unsigned)__builtin_amdgcn_update_dpp((int)lo, (int)lo, CTRL, RMASK, 0xF, false);
    double o = __longlong_as_double((long long)(((unsigned long long)th << 32) | tl));
    return fmax(v, o);
}

__device__ __forceinline__ int knn_bin(float d)
{
    int e = (int)(__float_as_uint(d) >> 23) - 90;   // monotone, clamped octave bins
    return e < 0 ? 0 : (e > 63 ? 63 : e);
}

// ---------------- mega kernel: 8 fps producers + 248 persistent workers --------
struct FpsS {
    float4 sxyz[NP];                    // 128 KB
    int sel[NS];                        // 8 KB
    unsigned long long rv64[2][FW];
};
struct KnnS {
    float sdist[NP];                    // 32 KB
    unsigned hist[32][KBINS];           // 8 KB
    float cd[MAXC];
    int   ci[MAXC];
    int   sidx[NK];
    float sf[NK][DIN];                  // 4 KB gathered feat rows
    float red[4][DOUT];                 // 2 KB cross-group max
    float wt[DIN * DOUT];               // 32 KB folded weights (LDS-resident)
    float cbv[DOUT];                    // 512 B folded bias
    unsigned ccnt;
    int cut;
};
union MegaS { FpsS f; KnnS k; };
// union = ~139 KB -> 1 block/CU; grid 256 -> all blocks co-resident,
// so producer progress never depends on dispatch order (deadlock-safe).

__global__ __launch_bounds__(MT, 1)
void mega_kernel(const float* __restrict__ coords, float* __restrict__ out_coords,
                 const float* __restrict__ feat, const float* __restrict__ W,
                 const float* __restrict__ bias, const float* __restrict__ gamma,
                 const float* __restrict__ beta, const float* __restrict__ rmean,
                 const float* __restrict__ rvar, float* __restrict__ outF,
                 unsigned* __restrict__ flags)
{
#pragma clang fp contract(off)
    __shared__ MegaS smem;
    const int t = threadIdx.x;

    if (blockIdx.x < NB) {
        // ================= FPS producer (1 block per batch) =================
        const int b = blockIdx.x;
        const float* cb = coords + (size_t)b * NP * 3;

        for (int i = t; i < NP; i += MT)
            smem.f.sxyz[i] = make_float4(cb[i * 3 + 0], cb[i * 3 + 1], cb[i * 3 + 2], 0.0f);
        __syncthreads();

        // points as float2 pairs: pair j holds indices t+2j*MT (lo), t+(2j+1)*MT (hi)
        // C-level vector ops (NO inline asm): compiler may emit v_pk_*_f32 or
        // scalarize — either way it keeps full scheduling freedom (R9's asm
        // regression: forced reg pairs + scheduling fence).
        v2f px2[FH], py2[FH], pz2[FH], dist2[FH];
#pragma unroll
        for (int j = 0; j < FH; ++j) {
            float4 plo = smem.f.sxyz[t + (2 * j) * MT];
            float4 phi = smem.f.sxyz[t + (2 * j + 1) * MT];
            px2[j] = (v2f){plo.x, phi.x};
            py2[j] = (v2f){plo.y, phi.y};
            pz2[j] = (v2f){plo.z, phi.z};
            dist2[j] = (v2f){1e10f, 1e10f};
        }

        const int wave = t >> 6, lane = t & 63;
        const unsigned nt = ~(unsigned)t;          // ~(t + k*MT) == nt - k*MT
        int cur = 0;

        for (int s = 0; s < NS; ++s) {
            if (t == 0) smem.f.sel[s] = cur;
            const float4 cc = smem.f.sxyz[cur];
            const v2f cx2 = {cc.x, cc.x}, cy2 = {cc.y, cc.y}, cz2 = {cc.z, cc.z};

            // per-component: d = fmaf(dz,dz,fmaf(dy,dy,dx*dx)); nd = fminf(dist,d)
            // -> bit-identical to the scalar R8 loop
            v2f mx2 = {-1.0f, -1.0f};
#pragma unroll
            for (int j = 0; j < FH; ++j) {
                v2f dx2 = px2[j] - cx2;
                v2f dy2 = py2[j] - cy2;
                v2f dz2 = pz2[j] - cz2;
                v2f d2 = dx2 * dx2;
                d2 = __builtin_elementwise_fma(dy2, dy2, d2);
                d2 = __builtin_elementwise_fma(dz2, dz2, d2);
                v2f nd2 = __builtin_elementwise_min(dist2[j], d2);
                dist2[j] = nd2;
                mx2 = __builtin_elementwise_max(mx2, nd2);
            }
            float m = fmaxf(mx2.x, mx2.y);
            // recover smallest k attaining m: independent compares -> or-tree -> ctz
            unsigned msk = 0;
#pragma unroll
            for (int j = 0; j < FH; ++j) {
                msk |= (dist2[j].x == m) ? (1u << (2 * j))     : 0u;
                msk |= (dist2[j].y == m) ? (1u << (2 * j + 1)) : 0u;
            }
            int kk = __builtin_ctz(msk);
            double best = pack_di(m, nt - (unsigned)(kk * MT));

            // wave argmax: 6 DPP f64-max levels -> lane 63 holds wave max
            best = dpp_max_f64<0xB1,  0xF>(best);  // quad_perm xor1
            best = dpp_max_f64<0x4E,  0xF>(best);  // quad_perm xor2
            best = dpp_max_f64<0x124, 0xF>(best);  // row_ror:4
            best = dpp_max_f64<0x128, 0xF>(best);  // row_ror:8
            best = dpp_max_f64<0x142, 0xA>(best);  // row_bcast15
            best = dpp_max_f64<0x143, 0xC>(best);  // row_bcast31

            int pb = s & 1;
            if (lane == 63) smem.f.rv64[pb][wave] = (unsigned long long)__double_as_longlong(best);
            __syncthreads();

            // cross-wave: b64 read of partial[lane&7]; period-8 values fully
            // reduce in 3 DPP levels (xor1, xor2, ror4)
            double g = __longlong_as_double((long long)smem.f.rv64[pb][lane & 7]);
            g = dpp_max_f64<0xB1,  0xF>(g);
            g = dpp_max_f64<0x4E,  0xF>(g);
            g = dpp_max_f64<0x124, 0xF>(g);
            cur = (int)~(unsigned)(unsigned long long)__double_as_longlong(g);

            // publish a 32-query granule (wave 0 only: program-order release
            // covers the wave's own coord stores)
            if ((s & 31) == 31) {
                int base = s - 31;
                if (t < 32) {
                    float4 p = smem.f.sxyz[smem.f.sel[base + t]];
                    float* dst = out_coords + ((size_t)b * NS + base + t) * 3;
                    dst[0] = p.x; dst[1] = p.y; dst[2] = p.z;
                }
                if (t == 0)
                    __hip_atomic_store(&flags[b * 16], (unsigned)((s + 1) >> 5),
                                       __ATOMIC_RELEASE, __HIP_MEMORY_SCOPE_AGENT);
            }
        }
    } else {
        // ===== persistent worker: knn + fused gather/MLP/max per query =====
        const int wid = blockIdx.x - NB;           // 0..247
        const int c = t & 31;
        const int o = t & (DOUT - 1);
        const int grp = t >> 7;                    // 0..3

        // fold BN into weights, LDS-resident (once per worker block);
        // identical expressions to the old fold kernel -> identical bits
        for (int i = t; i < DIN * DOUT; i += MT) {
            int oo = i & (DOUT - 1), kk = i >> 7;
            smem.k.wt[i] = W[oo * DIN + kk] * (gamma[oo] * rsqrtf(rvar[oo] + BN_EPS));
        }
        if (t < DOUT)
            smem.k.cbv[t] = (bias[t] - rmean[t]) * (gamma[t] * rsqrtf(rvar[t] + BN_EPS)) + beta[t];
        __syncthreads();

        for (int j = wid; j < NB * NS; j += NW) {
            const int s = j >> 3, b = j & 7;       // ascending s per worker
            const int q = b * NS + s;

            if (t == 0) {
                const unsigned need = (unsigned)(s >> 5) + 1;
                while (__hip_atomic_load(&flags[b * 16], __ATOMIC_ACQUIRE,
                                         __HIP_MEMORY_SCOPE_AGENT) < need)
                    __builtin_amdgcn_s_sleep(32);
            }
            __syncthreads();

            const float* cb = coords + (size_t)b * NP * 3;
            const float* qp = out_coords + (size_t)q * 3;
            const float qx = qp[0], qy = qp[1], qz = qp[2];

            for (int i = t; i < 32 * KBINS; i += MT) ((unsigned*)smem.k.hist)[i] = 0;
            if (t == 0) smem.k.ccnt = 0;
            __syncthreads();

            for (int jj = 0; jj < KJ; ++jj) {
                int i = t + jj * MT;
                float dx = cb[i * 3 + 0] - qx, dy = cb[i * 3 + 1] - qy, dz = cb[i * 3 + 2] - qz;
                float d = fmaf(dz, dz, fmaf(dy, dy, dx * dx));
                smem.k.sdist[i] = d;
                atomicAdd(&smem.k.hist[c][knn_bin(d)], 1u);
            }
            __syncthreads();

            if (t < 64) {
                unsigned total = 0;
#pragma unroll
                for (int cc = 0; cc < 32; ++cc) total += smem.k.hist[cc][t];
                unsigned incl = total;
#pragma unroll
                for (int off = 1; off < 64; off <<= 1) {
                    unsigned n = __shfl_up(incl, off);
                    if (t >= off) incl += n;
                }
                unsigned excl = incl - total;
                if (excl < NK && incl >= NK) smem.k.cut = t;
            }
            __syncthreads();

            const int cut = smem.k.cut;
            for (int jj = 0; jj < KJ; ++jj) {
                int i = t + jj * MT;
                float d = smem.k.sdist[i];
                if (knn_bin(d) <= cut) {
                    unsigned p = atomicAdd(&smem.k.ccnt, 1u);
                    if (p < MAXC) { smem.k.cd[p] = d; smem.k.ci[p] = i; }
                }
            }
            __syncthreads();

            // parallel rank-select: rank = #{(dj,ij) < (d,i)}; unique ranks -> LDS
            int cnt = (int)(smem.k.ccnt < (unsigned)MAXC ? smem.k.ccnt : (unsigned)MAXC);
            for (int p = t; p < cnt; p += MT) {
                float d = smem.k.cd[p]; int idx = smem.k.ci[p];
                int rank = 0;
                for (int jj = 0; jj < cnt; ++jj) {
                    float dj = smem.k.cd[jj]; int ij = smem.k.ci[jj];
                    rank += (dj < d || (dj == d && ij < idx)) ? 1 : 0;
                }
                if (rank < NK) smem.k.sidx[rank] = idx;
            }
            __syncthreads();

            // gather 16 neighbor feat rows (coalesced 256-B rows)
#pragma unroll
            for (int rr = 0; rr < 2; ++rr) {
                int row = (t >> 6) + rr * 8;       // 0..15
                smem.k.sf[row][t & 63] =
                    feat[((size_t)b * NP + smem.k.sidx[row]) * DIN + (t & 63)];
            }
            __syncthreads();

            // fused MLP+relu+max: thread handles out-channel o, neighbors
            // {grp, grp+4, grp+8, grp+12}; cross-group max via LDS
            const float cb0 = smem.k.cbv[o];
            float mx = -3.4e38f;
#pragma unroll
            for (int nn = 0; nn < 4; ++nn) {
                const float4* f4 = (const float4*)smem.k.sf[grp + nn * 4];
                float acc = cb0;
#pragma unroll
                for (int k4 = 0; k4 < DIN / 4; ++k4) {
                    float4 f = f4[k4];
                    acc = fmaf(f.x, smem.k.wt[(k4 * 4 + 0) * DOUT + o], acc);
                    acc = fmaf(f.y, smem.k.wt[(k4 * 4 + 1) * DOUT + o], acc);
                    acc = fmaf(f.z, smem.k.wt[(k4 * 4 + 2) * DOUT + o], acc);
                    acc = fmaf(f.w, smem.k.wt[(k4 * 4 + 3) * DOUT + o], acc);
                }
                mx = fmaxf(mx, fmaxf(acc, 0.0f));
            }
            smem.k.red[grp][o] = mx;
            __syncthreads();

            if (t < DOUT) {
                float v = fmaxf(fmaxf(smem.k.red[0][t], smem.k.red[1][t]),
                                fmaxf(smem.k.red[2][t], smem.k.red[3][t]));
                outF[(size_t)q * DOUT + t] = v;
            }
            __syncthreads();
        }
    }
}

extern "C" void kernel_launch(void* const* d_in, const int* in_sizes, int n_in,
                              void* d_out, int out_size, void* d_ws, size_t ws_size,
                              hipStream_t stream)
{
    const float* coords = (const float*)d_in[0];
    const float* feat   = (const float*)d_in[1];
    const float* W      = (const float*)d_in[2];
    const float* bias   = (const float*)d_in[3];
    const float* gamma  = (const float*)d_in[4];
    const float* beta   = (const float*)d_in[5];
    const float* rmean  = (const float*)d_in[6];
    const float* rvar   = (const float*)d_in[7];

    float* out_coords = (float*)d_out;                    // [8,2048,3]
    float* out_feat   = out_coords + (size_t)NB * NS * 3; // [8,2048,128]

    unsigned* flags = (unsigned*)d_ws;                    // 8 flags, 64B apart

    hipMemsetAsync(flags, 0, 8 * 16 * sizeof(unsigned), stream);
    mega_kernel<<<NB + NW, MT, 0, stream>>>(
        coords, out_coords, feat, W, bias, gamma, beta, rmean, rvar,
        out_feat, flags);
}

// Round 11
// 1673.966 us; speedup vs baseline: 1.2022x; 1.1295x over previous
//
#include <hip/hip_runtime.h>

#define NB   8
#define NP   8192
#define NS   2048
#define NK   16
#define DIN  64
#define DOUT 128
#define BN_EPS 1e-5f

#define MT   512            // mega-kernel block size
#define NW   248            // worker blocks (grid = 8 fps + 248 workers = 256 CUs)
#define FP   (NP / MT)      // 16 fps points per thread
#define FW   (MT / 64)      // 8 waves
#define KJ   (NP / MT)      // 16 knn points per thread
#define KBINS 64
#define MAXC 512

// ---------------- f64-packed argmax helpers --------------------------------------
// packed u64 = (fp32 dist bits << 32) | ~idx, as double (sign bit 0 -> numeric
// order == u64 order): fmax == (max dist, tie -> min idx).
__device__ __forceinline__ double pack_di(float d, unsigned lo)
{
    unsigned long long u = ((unsigned long long)__float_as_uint(d) << 32) | lo;
    return __longlong_as_double((long long)u);
}

template<int CTRL, int RMASK>
__device__ __forceinline__ double dpp_max_f64(double v)
{
    unsigned long long u = (unsigned long long)__double_as_longlong(v);
    unsigned hi = (unsigned)(u >> 32), lo = (unsigned)u;
    unsigned th = (unsigned)__builtin_amdgcn_update_dpp((int)hi, (int)hi, CTRL, RMASK, 0xF, false);
    unsigned tl = (unsigned)__builtin_amdgcn_update_dpp((int)lo, (int)lo, CTRL, RMASK, 0xF, false);
    double o = __longlong_as_double((long long)(((unsigned long long)th << 32) | tl));
    return fmax(v, o);
}

__device__ __forceinline__ int knn_bin(float d)
{
    int e = (int)(__float_as_uint(d) >> 23) - 90;   // monotone, clamped octave bins
    return e < 0 ? 0 : (e > 63 ? 63 : e);
}

// ---------------- mega kernel: 8 fps producers + 248 persistent workers --------
struct FpsS {
    float4 sxyz[NP];                    // 128 KB
    int sel[NS];                        // 8 KB
    unsigned long long rv64[2][FW];
};
struct KnnS {
    float sdist[NP];                    // 32 KB
    unsigned hist[32][KBINS];           // 8 KB
    float cd[MAXC];
    int   ci[MAXC];
    int   sidx[NK];
    float sf[NK][DIN];                  // 4 KB gathered feat rows
    float red[4][DOUT];                 // 2 KB cross-group max
    float wt[DIN * DOUT];               // 32 KB folded weights (LDS-resident)
    float cbv[DOUT];                    // 512 B folded bias
    unsigned ccnt;
    int cut;
};
union MegaS { FpsS f; KnnS k; };
// union = ~139 KB -> 1 block/CU; grid 256 -> all blocks co-resident,
// so producer progress never depends on dispatch order (deadlock-safe).

__global__ __launch_bounds__(MT, 1)
void mega_kernel(const float* __restrict__ coords, float* __restrict__ out_coords,
                 const float* __restrict__ feat, const float* __restrict__ W,
                 const float* __restrict__ bias, const float* __restrict__ gamma,
                 const float* __restrict__ beta, const float* __restrict__ rmean,
                 const float* __restrict__ rvar, float* __restrict__ outF,
                 unsigned* __restrict__ flags)
{
#pragma clang fp contract(off)
    __shared__ MegaS smem;
    const int t = threadIdx.x;

    if (blockIdx.x < NB) {
        // ================= FPS producer (1 block per batch) =================
        // R8's plain-scalar loop: measured twice that ANY pairing of these
        // arrays (inline asm R9, vector types R10) adds ~225 us — keep scalar.
        const int b = blockIdx.x;
        const float* cb = coords + (size_t)b * NP * 3;

        for (int i = t; i < NP; i += MT)
            smem.f.sxyz[i] = make_float4(cb[i * 3 + 0], cb[i * 3 + 1], cb[i * 3 + 2], 0.0f);
        __syncthreads();

        float px[FP], py[FP], pz[FP], dist[FP];
#pragma unroll
        for (int k = 0; k < FP; ++k) {
            float4 p = smem.f.sxyz[t + k * MT];
            px[k] = p.x; py[k] = p.y; pz[k] = p.z;
            dist[k] = 1e10f;
        }

        const int wave = t >> 6, lane = t & 63;
        const unsigned nt = ~(unsigned)t;          // ~(t + k*MT) == nt - k*MT
        int cur = 0;

        for (int s = 0; s < NS; ++s) {
            if (t == 0) smem.f.sel[s] = cur;
            const float4 cc = smem.f.sxyz[cur];
            const float cx = cc.x, cy = cc.y, cz = cc.z;

            // min-dist update + f32 dual-chain max (full-rate scalar)
            float m0 = -1.0f, m1 = -1.0f;
#pragma unroll
            for (int k = 0; k < FP; ++k) {
                float dx = px[k] - cx, dy = py[k] - cy, dz = pz[k] - cz;
                float d = fmaf(dz, dz, fmaf(dy, dy, dx * dx));
                float nd = fminf(dist[k], d);
                dist[k] = nd;
                if (k & 1) m1 = fmaxf(m1, nd);
                else       m0 = fmaxf(m0, nd);
            }
            float m = fmaxf(m0, m1);
            // recover smallest k attaining m: independent compares -> or-tree -> ctz
            unsigned msk = 0;
#pragma unroll
            for (int k = 0; k < FP; ++k)
                msk |= (dist[k] == m) ? (1u << k) : 0u;
            int kk = __builtin_ctz(msk);
            double best = pack_di(m, nt - (unsigned)(kk * MT));

            // wave argmax: 6 DPP f64-max levels -> lane 63 holds wave max
            best = dpp_max_f64<0xB1,  0xF>(best);  // quad_perm xor1
            best = dpp_max_f64<0x4E,  0xF>(best);  // quad_perm xor2
            best = dpp_max_f64<0x124, 0xF>(best);  // row_ror:4
            best = dpp_max_f64<0x128, 0xF>(best);  // row_ror:8
            best = dpp_max_f64<0x142, 0xA>(best);  // row_bcast15
            best = dpp_max_f64<0x143, 0xC>(best);  // row_bcast31

            int pb = s & 1;
            if (lane == 63) smem.f.rv64[pb][wave] = (unsigned long long)__double_as_longlong(best);
            __syncthreads();

            // cross-wave: b64 read of partial[lane&7]; period-8 values fully
            // reduce in 3 DPP levels (xor1, xor2, ror4) — verified R9/R10
            double g = __longlong_as_double((long long)smem.f.rv64[pb][lane & 7]);
            g = dpp_max_f64<0xB1,  0xF>(g);
            g = dpp_max_f64<0x4E,  0xF>(g);
            g = dpp_max_f64<0x124, 0xF>(g);
            cur = (int)~(unsigned)(unsigned long long)__double_as_longlong(g);

            // publish a 32-query granule (wave 0 only: program-order release
            // covers the wave's own coord stores)
            if ((s & 31) == 31) {
                int base = s - 31;
                if (t < 32) {
                    float4 p = smem.f.sxyz[smem.f.sel[base + t]];
                    float* dst = out_coords + ((size_t)b * NS + base + t) * 3;
                    dst[0] = p.x; dst[1] = p.y; dst[2] = p.z;
                }
                if (t == 0)
                    __hip_atomic_store(&flags[b * 16], (unsigned)((s + 1) >> 5),
                                       __ATOMIC_RELEASE, __HIP_MEMORY_SCOPE_AGENT);
            }
        }
    } else {
        // ===== persistent worker: knn + fused gather/MLP/max per query =====
        const int wid = blockIdx.x - NB;           // 0..247
        const int c = t & 31;
        const int o = t & (DOUT - 1);
        const int grp = t >> 7;                    // 0..3

        // fold BN into weights, LDS-resident (once per worker block);
        // identical expressions to the old fold kernel -> identical bits
        for (int i = t; i < DIN * DOUT; i += MT) {
            int oo = i & (DOUT - 1), kk = i >> 7;
            smem.k.wt[i] = W[oo * DIN + kk] * (gamma[oo] * rsqrtf(rvar[oo] + BN_EPS));
        }
        if (t < DOUT)
            smem.k.cbv[t] = (bias[t] - rmean[t]) * (gamma[t] * rsqrtf(rvar[t] + BN_EPS)) + beta[t];
        __syncthreads();

        for (int j = wid; j < NB * NS; j += NW) {
            const int s = j >> 3, b = j & 7;       // ascending s per worker
            const int q = b * NS + s;

            if (t == 0) {
                const unsigned need = (unsigned)(s >> 5) + 1;
                while (__hip_atomic_load(&flags[b * 16], __ATOMIC_ACQUIRE,
                                         __HIP_MEMORY_SCOPE_AGENT) < need)
                    __builtin_amdgcn_s_sleep(32);
            }
            __syncthreads();

            const float* cb = coords + (size_t)b * NP * 3;
            const float* qp = out_coords + (size_t)q * 3;
            const float qx = qp[0], qy = qp[1], qz = qp[2];

            for (int i = t; i < 32 * KBINS; i += MT) ((unsigned*)smem.k.hist)[i] = 0;
            if (t == 0) smem.k.ccnt = 0;
            __syncthreads();

            for (int jj = 0; jj < KJ; ++jj) {
                int i = t + jj * MT;
                float dx = cb[i * 3 + 0] - qx, dy = cb[i * 3 + 1] - qy, dz = cb[i * 3 + 2] - qz;
                float d = fmaf(dz, dz, fmaf(dy, dy, dx * dx));
                smem.k.sdist[i] = d;
                atomicAdd(&smem.k.hist[c][knn_bin(d)], 1u);
            }
            __syncthreads();

            if (t < 64) {
                unsigned total = 0;
#pragma unroll
                for (int cc = 0; cc < 32; ++cc) total += smem.k.hist[cc][t];
                unsigned incl = total;
#pragma unroll
                for (int off = 1; off < 64; off <<= 1) {
                    unsigned n = __shfl_up(incl, off);
                    if (t >= off) incl += n;
                }
                unsigned excl = incl - total;
                if (excl < NK && incl >= NK) smem.k.cut = t;
            }
            __syncthreads();

            const int cut = smem.k.cut;
            for (int jj = 0; jj < KJ; ++jj) {
                int i = t + jj * MT;
                float d = smem.k.sdist[i];
                if (knn_bin(d) <= cut) {
                    unsigned p = atomicAdd(&smem.k.ccnt, 1u);
                    if (p < MAXC) { smem.k.cd[p] = d; smem.k.ci[p] = i; }
                }
            }
            __syncthreads();

            // parallel rank-select: rank = #{(dj,ij) < (d,i)}; unique ranks -> LDS
            int cnt = (int)(smem.k.ccnt < (unsigned)MAXC ? smem.k.ccnt : (unsigned)MAXC);
            for (int p = t; p < cnt; p += MT) {
                float d = smem.k.cd[p]; int idx = smem.k.ci[p];
                int rank = 0;
                for (int jj = 0; jj < cnt; ++jj) {
                    float dj = smem.k.cd[jj]; int ij = smem.k.ci[jj];
                    rank += (dj < d || (dj == d && ij < idx)) ? 1 : 0;
                }
                if (rank < NK) smem.k.sidx[rank] = idx;
            }
            __syncthreads();

            // gather 16 neighbor feat rows (coalesced 256-B rows)
#pragma unroll
            for (int rr = 0; rr < 2; ++rr) {
                int row = (t >> 6) + rr * 8;       // 0..15
                smem.k.sf[row][t & 63] =
                    feat[((size_t)b * NP + smem.k.sidx[row]) * DIN + (t & 63)];
            }
            __syncthreads();

            // fused MLP+relu+max: thread handles out-channel o, neighbors
            // {grp, grp+4, grp+8, grp+12}; cross-group max via LDS
            const float cb0 = smem.k.cbv[o];
            float mx = -3.4e38f;
#pragma unroll
            for (int nn = 0; nn < 4; ++nn) {
                const float4* f4 = (const float4*)smem.k.sf[grp + nn * 4];
                float acc = cb0;
#pragma unroll
                for (int k4 = 0; k4 < DIN / 4; ++k4) {
                    float4 f = f4[k4];
                    acc = fmaf(f.x, smem.k.wt[(k4 * 4 + 0) * DOUT + o], acc);
                    acc = fmaf(f.y, smem.k.wt[(k4 * 4 + 1) * DOUT + o], acc);
                    acc = fmaf(f.z, smem.k.wt[(k4 * 4 + 2) * DOUT + o], acc);
                    acc = fmaf(f.w, smem.k.wt[(k4 * 4 + 3) * DOUT + o], acc);
                }
                mx = fmaxf(mx, fmaxf(acc, 0.0f));
            }
            smem.k.red[grp][o] = mx;
            __syncthreads();

            if (t < DOUT) {
                float v = fmaxf(fmaxf(smem.k.red[0][t], smem.k.red[1][t]),
                                fmaxf(smem.k.red[2][t], smem.k.red[3][t]));
                outF[(size_t)q * DOUT + t] = v;
            }
            __syncthreads();
        }
    }
}

extern "C" void kernel_launch(void* const* d_in, const int* in_sizes, int n_in,
                              void* d_out, int out_size, void* d_ws, size_t ws_size,
                              hipStream_t stream)
{
    const float* coords = (const float*)d_in[0];
    const float* feat   = (const float*)d_in[1];
    const float* W      = (const float*)d_in[2];
    const float* bias   = (const float*)d_in[3];
    const float* gamma  = (const float*)d_in[4];
    const float* beta   = (const float*)d_in[5];
    const float* rmean  = (const float*)d_in[6];
    const float* rvar   = (const float*)d_in[7];

    float* out_coords = (float*)d_out;                    // [8,2048,3]
    float* out_feat   = out_coords + (size_t)NB * NS * 3; // [8,2048,128]

    unsigned* flags = (unsigned*)d_ws;                    // 8 flags, 64B apart

    hipMemsetAsync(flags, 0, 8 * 16 * sizeof(unsigned), stream);
    mega_kernel<<<NB + NW, MT, 0, stream>>>(
        coords, out_coords, feat, W, bias, gamma, beta, rmean, rvar,
        out_feat, flags);
}